// Round 5
// baseline (443.527 us; speedup 1.0000x reference)
//
#include <hip/hip_runtime.h>
#include <hip/hip_bf16.h>
#include <stdint.h>

// Problem constants (head_2327872274482): B=1024, T=256, C=195, H=8
#define TT   256
#define CC   195
#define HH   8
#define NKT  7     // projection K-tiles of 32 (7*32 = 224 >= 195)
#define XSTR 200   // shorts per staged x row (195 -> pad 200; 400 B, 16B-aligned rows)
#define PSTR 40    // P-chunk row stride (shorts): 20 words -> 2-way (free)
#define VSTR 260   // fused-fallback Vt stride

typedef __attribute__((ext_vector_type(8))) short short8;  // bf16 MFMA A/B frag
typedef __attribute__((ext_vector_type(4))) float f32x4;   // MFMA C/D frag

static __device__ __forceinline__ short f2bf(float v) {
    union { __hip_bfloat16 h; short s; } cv;
    cv.h = __float2bfloat16(v);
    return cv.s;
}
static __device__ __forceinline__ uint32_t pkbf2(float a, float b) {
    return (uint32_t)(uint16_t)f2bf(a) | ((uint32_t)(uint16_t)f2bf(b) << 16);
}

// ============================================================================
// K1: projection. Block = 64 token rows. Coalesced stage -> LDS bf16 ->
// MFMA -> qkv to workspace in attention-ready layouts:
//   qk_g[token][0:16]  : q features 0..7, k features 8..15 (bf16, 32 B/row)
//   vt_g[b][h][t]      : V transposed per batch (bf16, 512 B/feature-row)
// ============================================================================
__global__ __launch_bounds__(256, 5)
void proj_kernel(const float* __restrict__ x,
                 const float* __restrict__ Wq,
                 const float* __restrict__ Wk,
                 const float* __restrict__ Wv,
                 short* __restrict__ qk_g,
                 short* __restrict__ vt_g)
{
    __shared__ short xs[64 * XSTR];   // 25,600 B -> 5 blocks/CU (w/ VGPR<=102)

    const int tid  = threadIdx.x;
    const int lane = tid & 63;
    const int wv   = __builtin_amdgcn_readfirstlane(tid >> 6);
    const int nn   = lane & 15;
    const int quad = lane >> 4;
    const size_t row0 = (size_t)blockIdx.x * 64;   // global token row
    const float* __restrict__ xb = x + row0 * CC;

    // B-frag preload (verified layout: B[k=quad*8+j][n=lane&15])
    const float* Wsel0 = (nn < 8) ? (Wq + nn) : (Wk + nn - 8);
    const float* Wsel1 = (nn < 8) ? (Wv + nn) : nullptr;
    short8 Bf[NKT][2];
#pragma unroll
    for (int kt = 0; kt < NKT; ++kt) {
#pragma unroll
        for (int j = 0; j < 8; ++j) {
            const int k = kt * 32 + quad * 8 + j;
            float v0 = (k < CC) ? Wsel0[(size_t)k * HH] : 0.f;
            float v1 = (k < CC && Wsel1) ? Wsel1[(size_t)k * HH] : 0.f;
            Bf[kt][0][j] = f2bf(v0);
            Bf[kt][1][j] = f2bf(v1);
        }
    }

    // ---- coalesced stage: linear word index w -> (row = w/100, colpair = w%100).
    // Consecutive lanes hit consecutive/near-consecutive addresses (vs R4's
    // 16-way row scatter). Pads cols 195..199 with zero.
    uint32_t* xsw = (uint32_t*)xs;
    for (int it = 0; it < 25; ++it) {
        const int w   = it * 256 + tid;        // 0..6399
        const int row = w / 100;               // magic-mul div
        const int cp  = w - row * 100;
        const int col = cp * 2;
        const float f0 = (col     < CC) ? xb[row * CC + col]     : 0.f;
        const float f1 = (col + 1 < CC) ? xb[row * CC + col + 1] : 0.f;
        xsw[w] = pkbf2(f0, f1);
    }
    __syncthreads();

    // ---- MFMA: wave strip = rows wv*16..+15; A-frag = ds_read_b128
    f32x4 acc0 = {0.f, 0.f, 0.f, 0.f};
    f32x4 acc1 = {0.f, 0.f, 0.f, 0.f};
    const short* arow = xs + (wv * 16 + nn) * XSTR;
#pragma unroll
    for (int kt = 0; kt < NKT; ++kt) {
        short8 a = (short8){0, 0, 0, 0, 0, 0, 0, 0};
        if (kt < 6 || quad == 0)               // kt=6 quads 1..3 are pure pad
            a = *reinterpret_cast<const short8*>(arow + kt * 32 + quad * 8);
        acc0 = __builtin_amdgcn_mfma_f32_16x16x32_bf16(a, Bf[kt][0], acc0, 0, 0, 0);
        acc1 = __builtin_amdgcn_mfma_f32_16x16x32_bf16(a, Bf[kt][1], acc1, 0, 0, 0);
    }
    // C/D layout: col = lane&15, row = quad*4 + reg
#pragma unroll
    for (int r = 0; r < 4; ++r) {
        const size_t trow = row0 + wv * 16 + quad * 4 + r;
        qk_g[trow * 16 + nn] = f2bf(acc0[r]);
        if (nn < 8) {
            const size_t bb = trow >> 8;
            const int    tt = (int)(trow & 255);
            vt_g[(bb * 8 + nn) * 256 + tt] = f2bf(acc1[r]);
        }
    }
}

// ============================================================================
// K2: MFMA causal attention (R4-verified math). Frags straight from global;
// LDS only for the per-wave P round-trip (5.1 KB). Block = half a batch.
// ============================================================================
__global__ __launch_bounds__(256, 4)
void attn_kernel(const short* __restrict__ qk_g,
                 const short* __restrict__ vt_g,
                 float* __restrict__ out)
{
    __shared__ short Pch[4 * 16 * PSTR];   // 5,120 B

    const int tid  = threadIdx.x;
    const int lane = tid & 63;
    const int wv   = __builtin_amdgcn_readfirstlane(tid >> 6);
    const int nn   = lane & 15;
    const int quad = lane >> 4;
    const int blk  = blockIdx.x;
    const int b    = blk >> 1;
    const int half = blk & 1;              // q-tiles 0..7 or 8..15

    const short* __restrict__ qkb = qk_g + (size_t)b * (TT * 16);
    const short* __restrict__ vtb = vt_g + (size_t)b * (HH * TT);

    // constant bV rows: n==8 -> ones (denom col), n>8 -> zeros
    short8 bVconst = (short8){0, 0, 0, 0, 0, 0, 0, 0};
    if (nn == 8) {
        const short one = (short)0x3F80;   // bf16 1.0
#pragma unroll
        for (int j = 0; j < 8; ++j) bVconst[j] = one;
    }

    const float SC2 = 0.07161149f * 1.44269504f;   // (1/sqrt(195)) * log2(e)
    short* Pw = Pch + wv * (16 * PSTR);

    for (int qi = 0; qi < 2; ++qi) {
        const int qt = half * 8 + (qi ? 7 - wv : wv);   // balanced pairing
        const int qb = qt * 16;

        short8 aQ = (short8){0, 0, 0, 0, 0, 0, 0, 0};
        if (quad == 0)
            aQ = *reinterpret_cast<const short8*>(qkb + (qb + nn) * 16);

        f32x4 accO = {0.f, 0.f, 0.f, 0.f};       // cols 0..7 = o_h, 8 = denom
        const int nch = (qt >> 1) + 1;
        for (int c = 0; c < nch; ++c) {
            const int kb = c * 32;
            asm volatile("" ::: "memory");        // keep E-writes after last P-read
#pragma unroll
            for (int h2 = 0; h2 < 2; ++h2) {
                const int kb16 = kb + h2 * 16;
                short8 bK = (short8){0, 0, 0, 0, 0, 0, 0, 0};
                if (quad == 0)
                    bK = *reinterpret_cast<const short8*>(qkb + (kb16 + nn) * 16 + 8);
                f32x4 s = __builtin_amdgcn_mfma_f32_16x16x32_bf16(
                              aQ, bK, (f32x4){0.f, 0.f, 0.f, 0.f}, 0, 0, 0);
                const int key = kb16 + nn;
#pragma unroll
                for (int r = 0; r < 4; ++r) {
                    const int qrow = qb + quad * 4 + r;
                    const float e = (key <= qrow) ? exp2f(s[r] * SC2) : 0.f;
                    Pw[(quad * 4 + r) * PSTR + h2 * 16 + nn] = f2bf(e);
                }
            }
            asm volatile("s_waitcnt lgkmcnt(0)" ::: "memory");
            const short8 aP = *reinterpret_cast<const short8*>(Pw + nn * PSTR + quad * 8);
            short8 bV = bVconst;
            if (nn < 8)
                bV = *reinterpret_cast<const short8*>(vtb + nn * TT + kb + quad * 8);
            accO = __builtin_amdgcn_mfma_f32_16x16x32_bf16(aP, bV, accO, 0, 0, 0);
        }
#pragma unroll
        for (int r = 0; r < 4; ++r) {
            const float dn = __shfl(accO[r], (lane & 48) | 8);
            if (nn < 8) {
                const int qrow = qb + quad * 4 + r;
                out[((size_t)b * TT + qrow) * HH + nn] = accO[r] / dn;
            }
        }
    }
}

// ============================================================================
// Fallback: R4's fused kernel (used only if ws_size is too small).
// ============================================================================
__global__ __launch_bounds__(256, 4)
void fused_head(const float* __restrict__ x,
                const float* __restrict__ Wq,
                const float* __restrict__ Wk,
                const float* __restrict__ Wv,
                float* __restrict__ out)
{
    __shared__ short Ql[TT * 8];
    __shared__ short Kl[TT * 8];
    __shared__ short Vt[16 * VSTR];
    __shared__ short Pch[4 * 16 * PSTR];

    const int tid  = threadIdx.x;
    const int lane = tid & 63;
    const int wv   = __builtin_amdgcn_readfirstlane(tid >> 6);
    const int b    = blockIdx.x;
    const int nn   = lane & 15;
    const int quad = lane >> 4;

    {
        uint32_t* vtw = (uint32_t*)Vt;
        const int base = (8 * VSTR) / 2;
        for (int i = tid; i < (8 * VSTR) / 2; i += 256)
            vtw[base + i] = (i < VSTR / 2) ? 0x3F803F80u : 0u;
    }

    const float* __restrict__ xb = x + (size_t)b * (TT * CC);
    const float* Wsel0 = (nn < 8) ? (Wq + nn) : (Wk + nn - 8);
    const float* Wsel1 = (nn < 8) ? (Wv + nn) : nullptr;
    short8 Bf[NKT][2];
#pragma unroll
    for (int kt = 0; kt < NKT; ++kt) {
#pragma unroll
        for (int j = 0; j < 8; ++j) {
            const int k = kt * 32 + quad * 8 + j;
            float v0 = (k < CC) ? Wsel0[(size_t)k * HH] : 0.f;
            float v1 = (k < CC && Wsel1) ? Wsel1[(size_t)k * HH] : 0.f;
            Bf[kt][0][j] = f2bf(v0);
            Bf[kt][1][j] = f2bf(v1);
        }
    }

    for (int ch = 0; ch < 4; ++ch) {
        const int rbase = ch * 64 + wv * 16;
        const float* __restrict__ xrow = xb + (size_t)(rbase + nn) * CC;
        f32x4 acc0 = {0.f, 0.f, 0.f, 0.f};
        f32x4 acc1 = {0.f, 0.f, 0.f, 0.f};
#pragma unroll
        for (int kt = 0; kt < NKT; ++kt) {
            float f[8];
#pragma unroll
            for (int j = 0; j < 8; ++j) {
                const int k = kt * 32 + quad * 8 + j;
                f[j] = (k < CC) ? xrow[k] : 0.f;
            }
            short8 a;
#pragma unroll
            for (int j = 0; j < 8; ++j) a[j] = f2bf(f[j]);
            acc0 = __builtin_amdgcn_mfma_f32_16x16x32_bf16(a, Bf[kt][0], acc0, 0, 0, 0);
            acc1 = __builtin_amdgcn_mfma_f32_16x16x32_bf16(a, Bf[kt][1], acc1, 0, 0, 0);
        }
#pragma unroll
        for (int r = 0; r < 4; ++r) {
            const int trow = rbase + quad * 4 + r;
            const short qs = f2bf(acc0[r]);
            if (nn < 8) {
                Ql[trow * 8 + nn] = qs;
                Vt[nn * VSTR + trow] = f2bf(acc1[r]);
            } else {
                Kl[trow * 8 + (nn - 8)] = qs;
            }
        }
    }
    __syncthreads();

    const float SC2 = 0.07161149f * 1.44269504f;
    const int qt4[4] = { wv, 7 - wv, 8 + wv, 15 - wv };
    short* Pw = Pch + wv * (16 * PSTR);

    for (int qi = 0; qi < 4; ++qi) {
        const int qt = qt4[qi];
        const int qb = qt * 16;
        short8 aQ = (short8){0, 0, 0, 0, 0, 0, 0, 0};
        if (quad == 0)
            aQ = *reinterpret_cast<const short8*>(Ql + (qb + nn) * 8);
        f32x4 accO = {0.f, 0.f, 0.f, 0.f};
        const int nch = (qt >> 1) + 1;
        for (int c = 0; c < nch; ++c) {
            const int kb = c * 32;
            asm volatile("" ::: "memory");
#pragma unroll
            for (int h2 = 0; h2 < 2; ++h2) {
                const int kb16 = kb + h2 * 16;
                short8 bK = (short8){0, 0, 0, 0, 0, 0, 0, 0};
                if (quad == 0)
                    bK = *reinterpret_cast<const short8*>(Kl + (kb16 + nn) * 8);
                f32x4 s = __builtin_amdgcn_mfma_f32_16x16x32_bf16(
                              aQ, bK, (f32x4){0.f, 0.f, 0.f, 0.f}, 0, 0, 0);
                const int key = kb16 + nn;
#pragma unroll
                for (int r = 0; r < 4; ++r) {
                    const int qrow = qb + quad * 4 + r;
                    const float e = (key <= qrow) ? exp2f(s[r] * SC2) : 0.f;
                    Pw[(quad * 4 + r) * PSTR + h2 * 16 + nn] = f2bf(e);
                }
            }
            asm volatile("s_waitcnt lgkmcnt(0)" ::: "memory");
            const short8 aP = *reinterpret_cast<const short8*>(Pw + nn * PSTR + quad * 8);
            const short8 bV = *reinterpret_cast<const short8*>(Vt + nn * VSTR + kb + quad * 8);
            accO = __builtin_amdgcn_mfma_f32_16x16x32_bf16(aP, bV, accO, 0, 0, 0);
        }
#pragma unroll
        for (int r = 0; r < 4; ++r) {
            const float dn = __shfl(accO[r], (lane & 48) | 8);
            if (nn < 8) {
                const int qrow = qb + quad * 4 + r;
                out[((size_t)b * TT + qrow) * HH + nn] = accO[r] / dn;
            }
        }
    }
}

extern "C" void kernel_launch(void* const* d_in, const int* in_sizes, int n_in,
                              void* d_out, int out_size, void* d_ws, size_t ws_size,
                              hipStream_t stream)
{
    const float* x  = (const float*)d_in[0];
    const float* Wq = (const float*)d_in[1];
    const float* Wk = (const float*)d_in[2];
    const float* Wv = (const float*)d_in[3];
    float* out      = (float*)d_out;
    const int B = in_sizes[0] / (TT * CC);   // = 1024

    const size_t need = (size_t)B * (TT * 16 + HH * TT) * sizeof(short); // 12.6 MB
    if (ws_size >= need) {
        short* qk_g = (short*)d_ws;
        short* vt_g = qk_g + (size_t)B * TT * 16;
        proj_kernel<<<dim3(B * 4), dim3(256), 0, stream>>>(x, Wq, Wk, Wv, qk_g, vt_g);
        attn_kernel<<<dim3(B * 2), dim3(256), 0, stream>>>(qk_g, vt_g, out);
    } else {
        fused_head<<<dim3(B), dim3(256), 0, stream>>>(x, Wq, Wk, Wv, out);
    }
}

// Round 6
// 321.497 us; speedup vs baseline: 1.3796x; 1.3796x over previous
//
#include <hip/hip_runtime.h>
#include <hip/hip_bf16.h>
#include <stdint.h>

// Problem constants (head_2327872274482): B=1024, T=256, C=195, H=8
#define TT   256
#define CC   195
#define HH   8
#define NKT  7     // projection K-tiles of 32 (7*32 = 224 >= 195)
#define XSTR 200   // shorts per staged x row (400 B, 16B-aligned rows)
#define WSTR 224   // shorts per Wt row (448 B, 16B-aligned)
#define VSTR 264   // shorts per Vt row (528 B, 16B-aligned)
#define PSTR 40    // shorts per P row (80 B, 16B-aligned)

typedef __attribute__((ext_vector_type(8))) short short8;  // bf16 MFMA A/B frag
typedef __attribute__((ext_vector_type(4))) float f32x4;   // MFMA C/D frag

static __device__ __forceinline__ short f2bf(float v) {
    union { __hip_bfloat16 h; short s; } cv;
    cv.h = __float2bfloat16(v);
    return cv.s;
}

// LDS map (manually packed, 16B-aligned):
//   xs  [4 waves][16 rows][XSTR]  25,600 B  (wave-private staging; Pch aliases it)
//   Wt  [24][WSTR]                10,752 B  (rows: q0..7,k0..7,v0..7, transposed W)
//   Ql  [256][8]                   4,096 B
//   Kl  [256][8]                   4,096 B
//   Vt  [16][VSTR]                 8,448 B  (rows 0..7 = v_h; 8 = ones; 9..15 = 0)
// total 52,992 B -> 3 blocks/CU
#define OFF_WT 25600
#define OFF_QL 36352
#define OFF_KL 40448
#define OFF_VT 44544

__global__ __launch_bounds__(256, 3)
void fused_head(const float* __restrict__ x,
                const float* __restrict__ Wq,
                const float* __restrict__ Wk,
                const float* __restrict__ Wv,
                float* __restrict__ out)
{
    __shared__ __align__(16) char smem[52992];
    short* xs = (short*)smem;
    short* Wt = (short*)(smem + OFF_WT);
    short* Ql = (short*)(smem + OFF_QL);
    short* Kl = (short*)(smem + OFF_KL);
    short* Vt = (short*)(smem + OFF_VT);
    short* Pch = xs;                       // alias: xs dead once attention starts

    const int tid  = threadIdx.x;
    const int lane = tid & 63;
    const int wv   = __builtin_amdgcn_readfirstlane(tid >> 6);
    const int b    = blockIdx.x;
    const int nn   = lane & 15;
    const int quad = lane >> 4;

    const float* __restrict__ xb = x + (size_t)b * (TT * CC);

    // ================= Phase A (pre-barrier init + W staging) =================
    // A1: zero Wt pad cols 195..223 (real data covers 0..194 -> disjoint, no race)
    for (int i = tid; i < 24 * 32; i += 256) {
        const int row = i >> 5, c = 192 + (i & 31);
        if (c >= CC) Wt[row * WSTR + c] = 0;
    }
    // A2: Vt const rows 8..15 over key cols 0..255 (row 8 = bf16 1.0, else 0)
    {
        uint32_t* vtw = (uint32_t*)Vt;
        for (int i = tid; i < 8 * 128; i += 256) {
            const int row = 8 + (i >> 7), w = i & 127;
            vtw[row * (VSTR / 2) + w] = (row == 8) ? 0x3F803F80u : 0u;
        }
    }
    // A3: zero xs pad cols 195..199 for all 64 staged rows (never overwritten)
    if (tid < 64) {
        short* xr = xs + (tid >> 4) * (16 * XSTR) + (tid & 15) * XSTR;
#pragma unroll
        for (int j = CC; j < XSTR; ++j) xr[j] = 0;
    }
    // A4: stage W -> Wt transposed (coalesced dword loads; scattered b16 LDS writes)
    for (int i = tid; i < 3 * CC * HH; i += 256) {
        const int m = i / (CC * HH);           // 0=q 1=k 2=v
        const int f = i - m * (CC * HH);       // c*8 + h
        const int c = f >> 3, h = f & 7;
        const float* Wp = (m == 0) ? Wq : (m == 1) ? Wk : Wv;
        Wt[(m * 8 + h) * WSTR + c] = f2bf(Wp[f]);
    }
    __syncthreads();   // barrier #1

    // ================= Phase B: B-fragment assembly (ds_read_b128) ============
    // 16x16x32 layout: B[k = quad*8+j][n = lane&15]; Wt row index == output o.
    short8 Bf[NKT][2];
#pragma unroll
    for (int kt = 0; kt < NKT; ++kt) {
        Bf[kt][0] = *reinterpret_cast<const short8*>(Wt + nn * WSTR + kt * 32 + quad * 8);
        Bf[kt][1] = (nn < 8)
            ? *reinterpret_cast<const short8*>(Wt + (16 + nn) * WSTR + kt * 32 + quad * 8)
            : (short8){0, 0, 0, 0, 0, 0, 0, 0};
    }

    // ================= Phase C: projection (zero barriers) ====================
    // Wave stages its own 16-row slab (3120 contiguous floats, 16B-aligned) via
    // 13 coalesced float4 loads, packs bf16 into its private xs region, then
    // MFMAs. Same-wave LDS RAW handled by lgkmcnt(0) (m120-verified pattern).
    short* xw = xs + wv * (16 * XSTR);
    for (int ch = 0; ch < 4; ++ch) {
        const int rbase = ch * 64 + wv * 16;
        const float4* slab = reinterpret_cast<const float4*>(xb + (size_t)rbase * CC);

        asm volatile("s_waitcnt lgkmcnt(0)" ::: "memory");  // WAR vs prev chunk reads
#pragma unroll
        for (int i = 0; i < 13; ++i) {
            const int idx = i * 64 + lane;                  // float4 index < 780
            if (idx < (16 * CC) / 4) {
                const float4 f = slab[idx];
                const int fi  = idx * 4;
                const int row = fi / 195;                   // magic-mul div
                const int c0  = fi - row * 195;
                short* dst = xw + row * XSTR + c0;
                const float fv[4] = {f.x, f.y, f.z, f.w};
#pragma unroll
                for (int j = 0; j < 4; ++j) {
                    // wrap into next row: +XSTR-195 = +5 shorts
                    const int adj = (c0 + j >= CC) ? (XSTR - CC) : 0;
                    dst[j + adj] = f2bf(fv[j]);
                }
            }
        }
        asm volatile("s_waitcnt lgkmcnt(0)" ::: "memory");  // RAW: writes -> frag reads

        f32x4 acc0 = {0.f, 0.f, 0.f, 0.f};
        f32x4 acc1 = {0.f, 0.f, 0.f, 0.f};
        const short* arow = xw + nn * XSTR;
#pragma unroll
        for (int kt = 0; kt < NKT; ++kt) {
            short8 a = (short8){0, 0, 0, 0, 0, 0, 0, 0};
            if (kt < 6 || quad == 0)            // kt=6 quads 1..3 = pure pad
                a = *reinterpret_cast<const short8*>(arow + kt * 32 + quad * 8);
            acc0 = __builtin_amdgcn_mfma_f32_16x16x32_bf16(a, Bf[kt][0], acc0, 0, 0, 0);
            acc1 = __builtin_amdgcn_mfma_f32_16x16x32_bf16(a, Bf[kt][1], acc1, 0, 0, 0);
        }
        // C/D layout: col = lane&15, row = quad*4 + reg  [m89-verified]
#pragma unroll
        for (int r = 0; r < 4; ++r) {
            const int trow = rbase + quad * 4 + r;
            const short qs = f2bf(acc0[r]);
            if (nn < 8) {
                Ql[trow * 8 + nn] = qs;
                Vt[nn * VSTR + trow] = f2bf(acc1[r]);
            } else {
                Kl[trow * 8 + (nn - 8)] = qs;
            }
        }
    }
    __syncthreads();   // barrier #2: proj -> attention

    // ================= Phase D: MFMA causal attention (R4-verified) ===========
    const float SC2 = 0.07161149f * 1.44269504f;   // (1/sqrt(195)) * log2(e)
    const int qt4[4] = { wv, 7 - wv, 8 + wv, 15 - wv };   // balanced: 34 units/wave
    short* Pw = Pch + wv * (16 * PSTR);

    for (int qi = 0; qi < 4; ++qi) {
        const int qt = qt4[qi];
        const int qb = qt * 16;

        short8 aQ = (short8){0, 0, 0, 0, 0, 0, 0, 0};
        if (quad == 0)
            aQ = *reinterpret_cast<const short8*>(Ql + (qb + nn) * 8);

        f32x4 accO = {0.f, 0.f, 0.f, 0.f};       // cols 0..7 = o_h, 8 = denom
        const int nch = (qt >> 1) + 1;
        for (int c = 0; c < nch; ++c) {
            const int kb = c * 32;
            asm volatile("" ::: "memory");        // keep E-writes after last P-read
#pragma unroll
            for (int h2 = 0; h2 < 2; ++h2) {
                const int kb16 = kb + h2 * 16;
                short8 bK = (short8){0, 0, 0, 0, 0, 0, 0, 0};
                if (quad == 0)
                    bK = *reinterpret_cast<const short8*>(Kl + (kb16 + nn) * 8);
                f32x4 s = __builtin_amdgcn_mfma_f32_16x16x32_bf16(
                              aQ, bK, (f32x4){0.f, 0.f, 0.f, 0.f}, 0, 0, 0);
                const int key = kb16 + nn;
#pragma unroll
                for (int r = 0; r < 4; ++r) {
                    const int qrow = qb + quad * 4 + r;
                    const float e = (key <= qrow) ? exp2f(s[r] * SC2) : 0.f;
                    Pw[(quad * 4 + r) * PSTR + h2 * 16 + nn] = f2bf(e);
                }
            }
            asm volatile("s_waitcnt lgkmcnt(0)" ::: "memory");
            const short8 aP = *reinterpret_cast<const short8*>(Pw + nn * PSTR + quad * 8);
            const short8 bV = *reinterpret_cast<const short8*>(Vt + nn * VSTR + kb + quad * 8);
            accO = __builtin_amdgcn_mfma_f32_16x16x32_bf16(aP, bV, accO, 0, 0, 0);
        }
#pragma unroll
        for (int r = 0; r < 4; ++r) {
            const float dn = __shfl(accO[r], (lane & 48) | 8);
            if (nn < 8) {
                const int qrow = qb + quad * 4 + r;
                out[((size_t)b * TT + qrow) * HH + nn] = accO[r] / dn;
            }
        }
    }
}

extern "C" void kernel_launch(void* const* d_in, const int* in_sizes, int n_in,
                              void* d_out, int out_size, void* d_ws, size_t ws_size,
                              hipStream_t stream)
{
    const float* x  = (const float*)d_in[0];
    const float* Wq = (const float*)d_in[1];
    const float* Wk = (const float*)d_in[2];
    const float* Wv = (const float*)d_in[3];
    float* out      = (float*)d_out;
    const int B = in_sizes[0] / (TT * CC);   // = 1024
    fused_head<<<dim3(B), dim3(256), 0, stream>>>(x, Wq, Wk, Wv, out);
}